// Round 1
// baseline (626.748 us; speedup 1.0000x reference)
//
#include <hip/hip_runtime.h>

#define NUM_HEADS 32
#define HEAD_DIM 128
#define NUM_KV_HEADS 8
#define SEQ 2048
#define BATCH 2
#define BQ 64           // q rows per block (16 per wave)
#define TKV 32          // kv rows per iteration
#define KSTR (HEAD_DIM + 8)   // 136 bf16 elems, padded: 2-way bank conflict only
#define VSTR (TKV + 8)        // 40
#define PSTR (TKV + 8)        // 40
#define QROWSTRIDE (NUM_HEADS * HEAD_DIM)      // 4096 floats
#define KROWSTRIDE (NUM_KV_HEADS * HEAD_DIM)   // 1024 floats

typedef __attribute__((ext_vector_type(8))) short bf16x8;   // MFMA A/B frag (4 VGPRs)
typedef __attribute__((ext_vector_type(4))) short bf16x4;   // 8-byte LDS write
typedef __attribute__((ext_vector_type(4))) float f32x4;    // MFMA C/D frag

// round-to-nearest-even f32 -> bf16 (bit trick; hardware-cheap)
__device__ __forceinline__ short f2bf(float f) {
    unsigned u = __float_as_uint(f);
    u += 0x7fffu + ((u >> 16) & 1u);
    return (short)(u >> 16);
}

__device__ __forceinline__ float fexp2(float x) {
    return __builtin_amdgcn_exp2f(x);
}

__global__ __launch_bounds__(256, 4)
void fattn_kernel(const float* __restrict__ qg, const float* __restrict__ kg,
                  const float* __restrict__ vg, float* __restrict__ outg) {
    const int tid  = threadIdx.x;
    const int wave = tid >> 6;
    const int lane = tid & 63;
    const int quad = lane >> 4;
    const int l16  = lane & 15;

    // heavy (high-q) tiles first for tail balance
    const int qt = (int)gridDim.x - 1 - (int)blockIdx.x;
    const int h  = blockIdx.y;
    const int b  = blockIdx.z;
    const int hk = h >> 2;            // GQA: 4 q-heads per kv-head (jnp.repeat order)
    const int q0 = qt * BQ;

    __shared__ short Kl[TKV * KSTR];            // K tile, row-major [kv][d]
    __shared__ short Vt[HEAD_DIM * VSTR];       // V tile, transposed [d][kv]
    __shared__ short Pl[4][16 * PSTR];          // per-wave P round-trip buffer

    // ---- load Q fragments once (A-layout: m=l16 -> q row, k=quad*8+j -> d) ----
    bf16x8 qf[4];
    {
        const int qrow = q0 + wave * 16 + l16;
        const float* qp = qg + (size_t)(b * SEQ + qrow) * QROWSTRIDE
                             + h * HEAD_DIM + quad * 8;
#pragma unroll
        for (int s = 0; s < 4; ++s) {
            float4 a = *(const float4*)(qp + s * 32);
            float4 c = *(const float4*)(qp + s * 32 + 4);
            bf16x8 f;
            f[0] = f2bf(a.x); f[1] = f2bf(a.y); f[2] = f2bf(a.z); f[3] = f2bf(a.w);
            f[4] = f2bf(c.x); f[5] = f2bf(c.y); f[6] = f2bf(c.z); f[7] = f2bf(c.w);
            qf[s] = f;
        }
    }

    f32x4 o[8];
#pragma unroll
    for (int i = 0; i < 8; ++i) o[i] = (f32x4){0.f, 0.f, 0.f, 0.f};
    float rm[4], rl[4];
#pragma unroll
    for (int r = 0; r < 4; ++r) { rm[r] = -1e30f; rl[r] = 0.f; }

    // fold softmax scale and log2(e) into the score domain
    const float sscale = 0.08838834764831845f * 1.4426950408889634f;
    const int ntk = (q0 + BQ) / TKV;   // causal: only tiles up to the diagonal

    for (int kt = 0; kt < ntk; ++kt) {
        const int kv0 = kt * TKV;
        __syncthreads();   // protect LDS from previous iteration's readers

        // ---- stage K tile: 32 rows x 128 cols, fp32 -> bf16 ----
        {
            const float* kbase = kg + (size_t)(b * SEQ + kv0) * KROWSTRIDE + hk * HEAD_DIM;
#pragma unroll
            for (int i = 0; i < 4; ++i) {
                int slot = i * 256 + tid;          // 1024 float4 slots
                int kvr = slot >> 5;
                int d4  = (slot & 31) * 4;
                float4 f = *(const float4*)(kbase + (size_t)kvr * KROWSTRIDE + d4);
                bf16x4 p4 = { f2bf(f.x), f2bf(f.y), f2bf(f.z), f2bf(f.w) };
                *(bf16x4*)&Kl[kvr * KSTR + d4] = p4;
            }
        }
        // ---- stage V tile transposed: each thread does a 4x4 block transpose ----
        {
            const int kvb = (tid & 7) * 4;
            const int db  = (tid >> 3) * 4;
            const float* vbase = vg + (size_t)(b * SEQ + kv0 + kvb) * KROWSTRIDE
                                    + hk * HEAD_DIM + db;
            float4 r0 = *(const float4*)(vbase);
            float4 r1 = *(const float4*)(vbase + KROWSTRIDE);
            float4 r2 = *(const float4*)(vbase + 2 * KROWSTRIDE);
            float4 r3 = *(const float4*)(vbase + 3 * KROWSTRIDE);
            bf16x4 c0 = { f2bf(r0.x), f2bf(r1.x), f2bf(r2.x), f2bf(r3.x) };
            bf16x4 c1 = { f2bf(r0.y), f2bf(r1.y), f2bf(r2.y), f2bf(r3.y) };
            bf16x4 c2 = { f2bf(r0.z), f2bf(r1.z), f2bf(r2.z), f2bf(r3.z) };
            bf16x4 c3 = { f2bf(r0.w), f2bf(r1.w), f2bf(r2.w), f2bf(r3.w) };
            *(bf16x4*)&Vt[(db + 0) * VSTR + kvb] = c0;
            *(bf16x4*)&Vt[(db + 1) * VSTR + kvb] = c1;
            *(bf16x4*)&Vt[(db + 2) * VSTR + kvb] = c2;
            *(bf16x4*)&Vt[(db + 3) * VSTR + kvb] = c3;
        }
        __syncthreads();

        // ---- S = Q * K^T (two 16-col kv tiles) ----
        f32x4 sacc[2];
#pragma unroll
        for (int nt = 0; nt < 2; ++nt) {
            f32x4 acc = {0.f, 0.f, 0.f, 0.f};
            const short* kp = &Kl[(nt * 16 + l16) * KSTR + quad * 8];
#pragma unroll
            for (int s = 0; s < 4; ++s) {
                bf16x8 bf = *(const bf16x8*)(kp + s * 32);
                acc = __builtin_amdgcn_mfma_f32_16x16x32_bf16(qf[s], bf, acc, 0, 0, 0);
            }
            sacc[nt] = acc;
        }

        // ---- masked online softmax (C-layout: row = quad*4+r, col = l16) ----
        const int qbase = q0 + wave * 16 + quad * 4;
        float p[2][4], alpha[4];
#pragma unroll
        for (int r = 0; r < 4; ++r) {
            float s0 = sacc[0][r] * sscale;
            float s1 = sacc[1][r] * sscale;
            const int qg_row = qbase + r;
            if (kv0 + l16 > qg_row)      s0 = -1e30f;
            if (kv0 + 16 + l16 > qg_row) s1 = -1e30f;
            float mx = fmaxf(s0, s1);
            mx = fmaxf(mx, __shfl_xor(mx, 1));
            mx = fmaxf(mx, __shfl_xor(mx, 2));
            mx = fmaxf(mx, __shfl_xor(mx, 4));
            mx = fmaxf(mx, __shfl_xor(mx, 8));
            float mn = fmaxf(rm[r], mx);
            float al = fexp2(rm[r] - mn);
            float p0 = fexp2(s0 - mn);
            float p1 = fexp2(s1 - mn);
            float ps = p0 + p1;
            ps += __shfl_xor(ps, 1);
            ps += __shfl_xor(ps, 2);
            ps += __shfl_xor(ps, 4);
            ps += __shfl_xor(ps, 8);
            rl[r] = rl[r] * al + ps;
            rm[r] = mn;
            alpha[r] = al;
            p[0][r] = p0; p[1][r] = p1;
        }
        // rescale O accumulators
#pragma unroll
        for (int dt = 0; dt < 8; ++dt)
#pragma unroll
            for (int r = 0; r < 4; ++r) o[dt][r] *= alpha[r];

        // ---- P: C-layout -> LDS -> A-layout (per-wave buffer, no barrier) ----
        short* pl = Pl[wave];
#pragma unroll
        for (int nt = 0; nt < 2; ++nt)
#pragma unroll
            for (int r = 0; r < 4; ++r)
                pl[(quad * 4 + r) * PSTR + nt * 16 + l16] = f2bf(p[nt][r]);
        bf16x8 af = *(const bf16x8*)&pl[l16 * PSTR + quad * 8];

        // ---- O += P * V (8 d-tiles of 16) ----
#pragma unroll
        for (int dt = 0; dt < 8; ++dt) {
            bf16x8 bf = *(const bf16x8*)&Vt[(dt * 16 + l16) * VSTR + quad * 8];
            o[dt] = __builtin_amdgcn_mfma_f32_16x16x32_bf16(af, bf, o[dt], 0, 0, 0);
        }
    }

    // ---- epilogue: normalize and store ----
#pragma unroll
    for (int r = 0; r < 4; ++r) {
        const float inv = 1.0f / rl[r];
        const int qrow = q0 + wave * 16 + quad * 4 + r;
        float* op = outg + (size_t)(b * SEQ + qrow) * QROWSTRIDE + h * HEAD_DIM + l16;
#pragma unroll
        for (int dt = 0; dt < 8; ++dt)
            op[dt * 16] = o[dt][r] * inv;
    }
}

extern "C" void kernel_launch(void* const* d_in, const int* in_sizes, int n_in,
                              void* d_out, int out_size, void* d_ws, size_t ws_size,
                              hipStream_t stream) {
    const float* q = (const float*)d_in[0];
    const float* k = (const float*)d_in[1];
    const float* v = (const float*)d_in[2];
    float* out = (float*)d_out;
    dim3 grid(SEQ / BQ, NUM_HEADS, BATCH);
    fattn_kernel<<<grid, dim3(256), 0, stream>>>(q, k, v, out);
}